// Round 8
// baseline (1903.521 us; speedup 1.0000x reference)
//
#include <hip/hip_runtime.h>
#include <cstdint>
#include <cstddef>

#define EE 1000000
#define NN 100000
#define NT 62500      // edge wave-tiles (16 edges each, exact)
#define NTN 6250      // node wave-tiles (16 nodes each, exact)

typedef unsigned short u16;
typedef __bf16 bf16x8 __attribute__((ext_vector_type(8)));
typedef float f32x4 __attribute__((ext_vector_type(4)));

__device__ __forceinline__ u16 f2bf(float f) {
    union { float f; uint32_t u; } v; v.f = f;
    uint32_t r = v.u + 0x7FFFu + ((v.u >> 16) & 1u);   // RNE
    return (u16)(r >> 16);
}
// RNE bf16 pair pack (compiler emits v_cvt_pk_bf16_f32): lo in bits[15:0]
__device__ __forceinline__ uint32_t cvt2(float lo, float hi) {
    u16 a = __builtin_bit_cast(u16, (__bf16)lo);
    u16 b = __builtin_bit_cast(u16, (__bf16)hi);
    return (uint32_t)a | ((uint32_t)b << 16);
}
__device__ __forceinline__ float bflo(uint32_t u) {
    union { uint32_t u; float f; } v; v.u = u << 16; return v.f;
}
__device__ __forceinline__ float bfhi(uint32_t u) {
    union { uint32_t u; float f; } v; v.u = u & 0xFFFF0000u; return v.f;
}

// ---------------- prep: pack weights into MFMA A-operand fragment streams.
// Frag formula (A-operand, 16x16x32): idx ((rt*4+kt)*64+lane)*8+j ->
//   W[koff + kt*32 + ((lane>>4)&3)*8 + j][rt*16 + (lane&15)]
// regions (u16 units): [0,16K) w1e (koff=0) | [16K,32K) w2 (K-perm)
//   | [32K,48K) w1s (koff=128) | [48K,64K) w1d (koff=256)
// consts at byte 131072 (f32): b1[128], b2[128], ln_g[128], ln_b[128]
__global__ void pack_weights_k(const float* __restrict__ W1, const float* __restrict__ W2,
                               const float* __restrict__ b1, const float* __restrict__ b2,
                               const float* __restrict__ lng, const float* __restrict__ lnb,
                               u16* __restrict__ pack) {
    int t = blockIdx.x * 256 + threadIdx.x;
    if (t >= 66048) return;
    if (t < 16384 || (t >= 32768 && t < 65536)) {
        int base = (t < 16384) ? 0 : (t < 49152) ? 32768 : 49152;
        int koff = (t < 16384) ? 0 : (t < 49152) ? 128 : 256;
        int u = t - base;
        int j = u & 7, lane = (u >> 3) & 63, kt = (u >> 9) & 3, rt = u >> 11;
        int k = koff + kt * 32 + ((lane >> 4) & 3) * 8 + j;
        pack[t] = f2bf(W1[k * 128 + rt * 16 + (lane & 15)]);
    } else if (t < 32768) {
        int u = t - 16384;
        int j = u & 7, lane = (u >> 3) & 63, kt2 = (u >> 9) & 3, ot = u >> 11;
        int hidden = 64 * (j >> 2) + 16 * kt2 + 4 * ((lane >> 4) & 3) + (j & 3);
        pack[t] = f2bf(W2[hidden * 128 + ot * 16 + (lane & 15)]);
    } else if (t < 66048) {
        int i = t - 65536;
        float v = (i < 128) ? b1[i] : (i < 256) ? b2[i - 128]
                : (i < 384) ? lng[i - 256] : lnb[i - 384];
        ((float*)(pack + 65536))[i] = v;
    }
}

// ---------------- node pass: uv[n] = [ u = W1s^T·nfeat[n] | v = W1d^T·nfeat[n] ]
// stored bf16 in MFMA-D distribution: uv[n*256 + hid] (u), uv[n*256+128+hid] (v)
__global__ void __launch_bounds__(256)
gen_uv_k(const float* __restrict__ nfeat, const u16* __restrict__ pack,
         u16* __restrict__ uv) {
    extern __shared__ char smem[];
    const u16* w1s = (const u16*)smem;            // 32 KB
    const u16* w1d = (const u16*)(smem + 32768);  // 32 KB
    const int tid = threadIdx.x;
    {
        const uint4* g = (const uint4*)(pack + 32768);  // bytes [65536,131072)
        uint4* l = (uint4*)smem;
#pragma unroll
        for (int i = 0; i < 16; i++) l[tid + i * 256] = g[tid + i * 256];
    }
    __syncthreads();
    const int lane = tid & 63, wid = tid >> 6;
    const int col = lane & 15, g4 = (lane >> 4) & 3;

    for (int nt = blockIdx.x * 4 + wid; nt < NTN; nt += (int)gridDim.x * 4) {
        const int n0 = nt * 16 + col;
        const float* rowN = nfeat + (size_t)n0 * 128;
        float4 nk[8];
#pragma unroll
        for (int q = 0; q < 4; q++) {
            const float4* p = (const float4*)(rowN + q * 32 + g4 * 8);
            nk[2 * q] = p[0]; nk[2 * q + 1] = p[1];
        }
        f32x4 au[8] = {}, av[8] = {};
#pragma unroll
        for (int kt = 0; kt < 4; kt++) {
            bf16x8 bf; uint32_t* bu = (uint32_t*)&bf;
            bu[0] = cvt2(nk[2 * kt].x, nk[2 * kt].y);
            bu[1] = cvt2(nk[2 * kt].z, nk[2 * kt].w);
            bu[2] = cvt2(nk[2 * kt + 1].x, nk[2 * kt + 1].y);
            bu[3] = cvt2(nk[2 * kt + 1].z, nk[2 * kt + 1].w);
#pragma unroll
            for (int rt = 0; rt < 8; rt++) {
                bf16x8 as = *(const bf16x8*)(w1s + ((rt * 4 + kt) * 64 + lane) * 8);
                bf16x8 ad = *(const bf16x8*)(w1d + ((rt * 4 + kt) * 64 + lane) * 8);
                au[rt] = __builtin_amdgcn_mfma_f32_16x16x32_bf16(as, bf, au[rt], 0, 0, 0);
                av[rt] = __builtin_amdgcn_mfma_f32_16x16x32_bf16(ad, bf, av[rt], 0, 0, 0);
            }
        }
        u16* urow = uv + (size_t)n0 * 256;
#pragma unroll
        for (int rt = 0; rt < 8; rt++) {
            uint2 pu, pv;
            pu.x = cvt2(au[rt][0], au[rt][1]); pu.y = cvt2(au[rt][2], au[rt][3]);
            pv.x = cvt2(av[rt][0], av[rt][1]); pv.y = cvt2(av[rt][2], av[rt][3]);
            *(uint2*)(urow + rt * 16 + g4 * 4) = pu;
            *(uint2*)(urow + 128 + rt * 16 + g4 * 4) = pv;
        }
    }
}

// ---------------- output[1] = nfeat passthrough
__global__ void copy_nfeat_k(const float4* __restrict__ s, float4* __restrict__ d, int n) {
    for (int i = blockIdx.x * blockDim.x + threadIdx.x; i < n; i += gridDim.x * blockDim.x)
        d[i] = s[i];
}

// ---------------- edge pass: h = silu(W1e·e + u[src] + v[dst] + b1);
// out = LN(h·W2 + b2) + e.
// 512 threads = 8 waves; 66 KB LDS; __launch_bounds__(512,4) caps total regs at
// 128 (ledger ~118: efk 32 + acc 32 shared + uvg 16 + hpk 16 + misc) so TWO
// blocks co-reside per CU (16 waves). Residual comes from the live efk regs via
// a 4-lane output transpose (no efeat re-read, −512 MB); uv gathered one tile
// ahead; next-tile efk loads interleaved into the store loop.
__global__ void __launch_bounds__(512, 4)
edge_mlp_k(const float* __restrict__ efeat, const int* __restrict__ srci,
           const int* __restrict__ dsti, const u16* __restrict__ uv,
           const u16* __restrict__ pack, float* __restrict__ out) {
    extern __shared__ char smem[];
    const u16* w1e = (const u16*)smem;               // 32 KB
    const u16* w2  = (const u16*)(smem + 32768);     // 32 KB
    const float* cst = (const float*)(smem + 65536); // 2 KB
    const int tid = threadIdx.x;
    {
        const uint4* g = (const uint4*)pack;   // 4096 uint4 = 64 KB
        uint4* l = (uint4*)smem;
#pragma unroll
        for (int i = 0; i < 8; i++) l[tid + i * 512] = g[tid + i * 512];
        ((float*)(smem + 65536))[tid] = ((const float*)(pack + 65536))[tid];
    }
    __syncthreads();

    const int lane = tid & 63, wid = tid >> 6;
    const int col = lane & 15, g4 = (lane >> 4) & 3;
    const bool g4hi = (g4 & 2) != 0;
    const int sl_lo = col + ((g4 & 1) << 5);   // transpose source lanes
    const int sl_hi = sl_lo + 16;
    const float* cb1 = cst;
    const float* cb2 = cst + 128;
    const float* cg  = cst + 256;
    const float* cbb = cst + 384;

    int wt = blockIdx.x * 8 + wid;
    const int stride = (int)gridDim.x * 8;

    // prologue: tile-0 indices, efeat row (B-layout), uv gather for tile 0
    const int e0 = wt * 16 + col;
    const int sn0 = srci[e0], dn0 = dsti[e0];
    float4 efk[8];
    {
        const float* rowE = efeat + (size_t)e0 * 128;
#pragma unroll
        for (int q = 0; q < 4; q++) {
            const float4* p = (const float4*)(rowE + q * 32 + g4 * 8);
            efk[2 * q] = p[0]; efk[2 * q + 1] = p[1];
        }
    }
    uint2 ug[8], vg[8];
    {
        const u16* up = uv + (size_t)sn0 * 256;
        const u16* vp = uv + (size_t)dn0 * 256 + 128;
#pragma unroll
        for (int rt = 0; rt < 8; rt++) {
            ug[rt] = *(const uint2*)(up + rt * 16 + g4 * 4);
            vg[rt] = *(const uint2*)(vp + rt * 16 + g4 * 4);
        }
    }

    for (; wt < NT; wt += stride) {
        // next-tile indices (uv + efk for t+1 are issued later this iteration)
        const int wtn = wt + stride;
        const int en = ((wtn < NT) ? wtn : wt) * 16 + col;
        const int sn1 = srci[en], dn1 = dsti[en];
        const float* rowEn = efeat + (size_t)en * 128;

        // ---- GEMM1 (K=128, efeat only): 32 MFMAs from efk + LDS
        f32x4 acc[8] = {};
#pragma unroll
        for (int kt = 0; kt < 4; kt++) {
            bf16x8 bf; uint32_t* bu = (uint32_t*)&bf;
            bu[0] = cvt2(efk[2 * kt].x, efk[2 * kt].y);
            bu[1] = cvt2(efk[2 * kt].z, efk[2 * kt].w);
            bu[2] = cvt2(efk[2 * kt + 1].x, efk[2 * kt + 1].y);
            bu[3] = cvt2(efk[2 * kt + 1].z, efk[2 * kt + 1].w);
#pragma unroll
            for (int rt = 0; rt < 8; rt++) {
                bf16x8 a = *(const bf16x8*)(w1e + ((rt * 4 + kt) * 64 + lane) * 8);
                acc[rt] = __builtin_amdgcn_mfma_f32_16x16x32_bf16(a, bf, acc[rt], 0, 0, 0);
            }
        }

        // ---- SiLU(acc + u + v + b1) -> packed bf16 (uvg of this tile consumed)
        uint32_t hpk[8][2];
#pragma unroll
        for (int rt = 0; rt < 8; rt++) {
            float4 b1v = *(const float4*)(cb1 + rt * 16 + g4 * 4);
            float x0 = acc[rt][0] + bflo(ug[rt].x) + bflo(vg[rt].x) + b1v.x;
            float x1 = acc[rt][1] + bfhi(ug[rt].x) + bfhi(vg[rt].x) + b1v.y;
            float x2 = acc[rt][2] + bflo(ug[rt].y) + bflo(vg[rt].y) + b1v.z;
            float x3 = acc[rt][3] + bfhi(ug[rt].y) + bfhi(vg[rt].y) + b1v.w;
            float s0 = x0 / (1.f + __expf(-x0)), s1 = x1 / (1.f + __expf(-x1));
            float s2 = x2 / (1.f + __expf(-x2)), s3 = x3 / (1.f + __expf(-x3));
            hpk[rt][0] = cvt2(s0, s1);
            hpk[rt][1] = cvt2(s2, s3);
        }

        // ---- issue next tile's uv gather (in flight for a full loop)
        {
            const u16* up = uv + (size_t)sn1 * 256;
            const u16* vp = uv + (size_t)dn1 * 256 + 128;
#pragma unroll
            for (int rt = 0; rt < 8; rt++) {
                ug[rt] = *(const uint2*)(up + rt * 16 + g4 * 4);
                vg[rt] = *(const uint2*)(vp + rt * 16 + g4 * 4);
            }
        }

        // ---- GEMM2 (acc reused: re-zero, accumulate)
#pragma unroll
        for (int ot = 0; ot < 8; ot++) acc[ot] = (f32x4){0.f, 0.f, 0.f, 0.f};
#pragma unroll
        for (int kt2 = 0; kt2 < 4; kt2++) {
            bf16x8 bf; uint32_t* bu = (uint32_t*)&bf;
            bu[0] = hpk[kt2][0];     bu[1] = hpk[kt2][1];
            bu[2] = hpk[kt2 + 4][0]; bu[3] = hpk[kt2 + 4][1];
#pragma unroll
            for (int ot = 0; ot < 8; ot++) {
                bf16x8 a = *(const bf16x8*)(w2 + ((ot * 4 + kt2) * 64 + lane) * 8);
                acc[ot] = __builtin_amdgcn_mfma_f32_16x16x32_bf16(a, bf, acc[ot], 0, 0, 0);
            }
        }

        // ---- + b2, LN stats (in-lane 32 + quad shfl reduce)
        float ssum = 0.f, qsum = 0.f;
#pragma unroll
        for (int ot = 0; ot < 8; ot++) {
            float4 b2v = *(const float4*)(cb2 + ot * 16 + g4 * 4);
#pragma unroll
            for (int r = 0; r < 4; r++) {
                float x = acc[ot][r] + ((const float*)&b2v)[r];
                acc[ot][r] = x;
                ssum += x; qsum += x * x;
            }
        }
        ssum += __shfl_xor(ssum, 16); qsum += __shfl_xor(qsum, 16);
        ssum += __shfl_xor(ssum, 32); qsum += __shfl_xor(qsum, 32);
        const float mean = ssum * (1.f / 128.f);
        const float rstd = rsqrtf(qsum * (1.f / 128.f) - mean * mean + 1e-5f);

        // ---- normalize in D-layout
#pragma unroll
        for (int ot = 0; ot < 8; ot++) {
            float4 gv = *(const float4*)(cg + ot * 16 + g4 * 4);
            float4 bv = *(const float4*)(cbb + ot * 16 + g4 * 4);
#pragma unroll
            for (int r = 0; r < 4; r++)
                acc[ot][r] = (acc[ot][r] - mean) * rstd * ((const float*)&gv)[r]
                           + ((const float*)&bv)[r];
        }

        // ---- transpose D-layout -> efk layout, + residual (live efk regs),
        //      contiguous 128B/quad stores; refill efk with next tile per q.
        // target float f = q*32 + g4*8 + j lives at src lane (2g4+(j>>2))&3,
        // reg ot = 2q + (g4>>1), elem j&3. Two broadcast passes (A=reg 2q,
        // B=reg 2q+1) + select by g4>=2.
        float* opf = out + (size_t)(wt * 16 + col) * 128;
#pragma unroll
        for (int qq = 0; qq < 4; qq++) {
            float lo[4], hi[4];
#pragma unroll
            for (int r = 0; r < 4; r++) {
                float av = acc[2 * qq][r], bv = acc[2 * qq + 1][r];
                float la = __shfl(av, sl_lo), lb = __shfl(bv, sl_lo);
                float ha = __shfl(av, sl_hi), hb = __shfl(bv, sl_hi);
                lo[r] = g4hi ? lb : la;
                hi[r] = g4hi ? hb : ha;
            }
            float4 olo, ohi;
            olo.x = lo[0] + efk[2 * qq].x; olo.y = lo[1] + efk[2 * qq].y;
            olo.z = lo[2] + efk[2 * qq].z; olo.w = lo[3] + efk[2 * qq].w;
            ohi.x = hi[0] + efk[2 * qq + 1].x; ohi.y = hi[1] + efk[2 * qq + 1].y;
            ohi.z = hi[2] + efk[2 * qq + 1].z; ohi.w = hi[3] + efk[2 * qq + 1].w;
            *(float4*)(opf + qq * 32 + g4 * 8) = olo;
            *(float4*)(opf + qq * 32 + g4 * 8 + 4) = ohi;
            // efk slot now dead -> prefetch next tile's quarter qq
            const float4* p = (const float4*)(rowEn + qq * 32 + g4 * 8);
            efk[2 * qq] = p[0]; efk[2 * qq + 1] = p[1];
        }
    }
}

extern "C" void kernel_launch(void* const* d_in, const int* in_sizes, int n_in,
                              void* d_out, int out_size, void* d_ws, size_t ws_size,
                              hipStream_t stream) {
    const float* efeat = (const float*)d_in[0];
    const float* nfeat = (const float*)d_in[1];
    const int* srci = (const int*)d_in[2];
    const int* dsti = (const int*)d_in[3];
    const float* W1 = (const float*)d_in[4];
    const float* b1 = (const float*)d_in[5];
    const float* W2 = (const float*)d_in[6];
    const float* b2 = (const float*)d_in[7];
    const float* lng = (const float*)d_in[8];
    const float* lnb = (const float*)d_in[9];
    float* out = (float*)d_out;

    const size_t pack_bytes = 133120;                 // 128 KB frags + 2 KB consts
    const size_t uv_bytes = (size_t)NN * 256 * 2;     // 51.2 MB bf16 uv
    u16 *pack, *uvb;
    if (ws_size >= pack_bytes + uv_bytes) {
        pack = (u16*)d_ws;
        uvb = (u16*)((char*)d_ws + pack_bytes);
    } else if (ws_size >= uv_bytes) {
        uvb = (u16*)d_ws;
        pack = (u16*)(out + (size_t)EE * 128);        // nfeat region; copy runs last
    } else {
        uvb = (u16*)(out + (size_t)EE * 128);         // exact fit; copy runs last
        pack = (ws_size >= pack_bytes) ? (u16*)d_ws
             : (u16*)(out + (size_t)EE * 128 - 33280); // edge-out tail (written last)
    }

    hipFuncSetAttribute(reinterpret_cast<const void*>(gen_uv_k),
                        hipFuncAttributeMaxDynamicSharedMemorySize, 65536);
    hipFuncSetAttribute(reinterpret_cast<const void*>(edge_mlp_k),
                        hipFuncAttributeMaxDynamicSharedMemorySize, 67584);

    pack_weights_k<<<258, 256, 0, stream>>>(W1, W2, b1, b2, lng, lnb, pack);
    gen_uv_k<<<512, 256, 65536, stream>>>(nfeat, pack, uvb);
    edge_mlp_k<<<512, 512, 67584, stream>>>(efeat, srci, dsti, uvb, pack, out);
    copy_nfeat_k<<<2048, 256, 0, stream>>>((const float4*)nfeat,
                                           (float4*)(out + (size_t)EE * 128),
                                           (NN * 128) / 4);
}

// Round 9
// 1329.986 us; speedup vs baseline: 1.4312x; 1.4312x over previous
//
#include <hip/hip_runtime.h>
#include <cstdint>
#include <cstddef>

#define EE 1000000
#define NN 100000
#define NT32 31250    // edge wave-tiles (32 edges each, exact)
#define NTN 6250      // node wave-tiles (16 nodes each, exact)

typedef unsigned short u16;
typedef __bf16 bf16x8 __attribute__((ext_vector_type(8)));
typedef float f32x4 __attribute__((ext_vector_type(4)));

__device__ __forceinline__ u16 f2bf(float f) {
    union { float f; uint32_t u; } v; v.f = f;
    uint32_t r = v.u + 0x7FFFu + ((v.u >> 16) & 1u);   // RNE
    return (u16)(r >> 16);
}
// RNE bf16 pair pack (compiler emits v_cvt_pk_bf16_f32): lo in bits[15:0]
__device__ __forceinline__ uint32_t cvt2(float lo, float hi) {
    u16 a = __builtin_bit_cast(u16, (__bf16)lo);
    u16 b = __builtin_bit_cast(u16, (__bf16)hi);
    return (uint32_t)a | ((uint32_t)b << 16);
}
__device__ __forceinline__ float bflo(uint32_t u) {
    union { uint32_t u; float f; } v; v.u = u << 16; return v.f;
}
__device__ __forceinline__ float bfhi(uint32_t u) {
    union { uint32_t u; float f; } v; v.u = u & 0xFFFF0000u; return v.f;
}

// ---------------- prep: pack weights into MFMA A-operand fragment streams.
// Frag formula (A-operand, 16x16x32): idx ((rt*4+kt)*64+lane)*8+j ->
//   W[koff + kt*32 + ((lane>>4)&3)*8 + j][rt*16 + (lane&15)]
// regions (u16 units): [0,16K) w1e (koff=0) | [16K,32K) w2 (K-perm)
//   | [32K,48K) w1s (koff=128) | [48K,64K) w1d (koff=256)
// consts at byte 131072 (f32): b1[128], b2[128], ln_g[128], ln_b[128]
__global__ void pack_weights_k(const float* __restrict__ W1, const float* __restrict__ W2,
                               const float* __restrict__ b1, const float* __restrict__ b2,
                               const float* __restrict__ lng, const float* __restrict__ lnb,
                               u16* __restrict__ pack) {
    int t = blockIdx.x * 256 + threadIdx.x;
    if (t >= 66048) return;
    if (t < 16384 || (t >= 32768 && t < 65536)) {
        int base = (t < 16384) ? 0 : (t < 49152) ? 32768 : 49152;
        int koff = (t < 16384) ? 0 : (t < 49152) ? 128 : 256;
        int u = t - base;
        int j = u & 7, lane = (u >> 3) & 63, kt = (u >> 9) & 3, rt = u >> 11;
        int k = koff + kt * 32 + ((lane >> 4) & 3) * 8 + j;
        pack[t] = f2bf(W1[k * 128 + rt * 16 + (lane & 15)]);
    } else if (t < 32768) {
        int u = t - 16384;
        int j = u & 7, lane = (u >> 3) & 63, kt2 = (u >> 9) & 3, ot = u >> 11;
        int hidden = 64 * (j >> 2) + 16 * kt2 + 4 * ((lane >> 4) & 3) + (j & 3);
        pack[t] = f2bf(W2[hidden * 128 + ot * 16 + (lane & 15)]);
    } else if (t < 66048) {
        int i = t - 65536;
        float v = (i < 128) ? b1[i] : (i < 256) ? b2[i - 128]
                : (i < 384) ? lng[i - 256] : lnb[i - 384];
        ((float*)(pack + 65536))[i] = v;
    }
}

// ---------------- node pass: uv[n] = [ u = W1s^T·nfeat[n] | v = W1d^T·nfeat[n] ]
// stored bf16 in MFMA-D distribution: uv[n*256 + hid] (u), uv[n*256+128+hid] (v)
__global__ void __launch_bounds__(256)
gen_uv_k(const float* __restrict__ nfeat, const u16* __restrict__ pack,
         u16* __restrict__ uv) {
    extern __shared__ char smem[];
    const u16* w1s = (const u16*)smem;            // 32 KB
    const u16* w1d = (const u16*)(smem + 32768);  // 32 KB
    const int tid = threadIdx.x;
    {
        const uint4* g = (const uint4*)(pack + 32768);  // bytes [65536,131072)
        uint4* l = (uint4*)smem;
#pragma unroll
        for (int i = 0; i < 16; i++) l[tid + i * 256] = g[tid + i * 256];
    }
    __syncthreads();
    const int lane = tid & 63, wid = tid >> 6;
    const int col = lane & 15, g4 = (lane >> 4) & 3;

    for (int nt = blockIdx.x * 4 + wid; nt < NTN; nt += (int)gridDim.x * 4) {
        const int n0 = nt * 16 + col;
        const float* rowN = nfeat + (size_t)n0 * 128;
        float4 nk[8];
#pragma unroll
        for (int q = 0; q < 4; q++) {
            const float4* p = (const float4*)(rowN + q * 32 + g4 * 8);
            nk[2 * q] = p[0]; nk[2 * q + 1] = p[1];
        }
        f32x4 au[8] = {}, av[8] = {};
#pragma unroll
        for (int kt = 0; kt < 4; kt++) {
            bf16x8 bf; uint32_t* bu = (uint32_t*)&bf;
            bu[0] = cvt2(nk[2 * kt].x, nk[2 * kt].y);
            bu[1] = cvt2(nk[2 * kt].z, nk[2 * kt].w);
            bu[2] = cvt2(nk[2 * kt + 1].x, nk[2 * kt + 1].y);
            bu[3] = cvt2(nk[2 * kt + 1].z, nk[2 * kt + 1].w);
#pragma unroll
            for (int rt = 0; rt < 8; rt++) {
                bf16x8 as = *(const bf16x8*)(w1s + ((rt * 4 + kt) * 64 + lane) * 8);
                bf16x8 ad = *(const bf16x8*)(w1d + ((rt * 4 + kt) * 64 + lane) * 8);
                au[rt] = __builtin_amdgcn_mfma_f32_16x16x32_bf16(as, bf, au[rt], 0, 0, 0);
                av[rt] = __builtin_amdgcn_mfma_f32_16x16x32_bf16(ad, bf, av[rt], 0, 0, 0);
            }
        }
        u16* urow = uv + (size_t)n0 * 256;
#pragma unroll
        for (int rt = 0; rt < 8; rt++) {
            uint2 pu, pv;
            pu.x = cvt2(au[rt][0], au[rt][1]); pu.y = cvt2(au[rt][2], au[rt][3]);
            pv.x = cvt2(av[rt][0], av[rt][1]); pv.y = cvt2(av[rt][2], av[rt][3]);
            *(uint2*)(urow + rt * 16 + g4 * 4) = pu;
            *(uint2*)(urow + 128 + rt * 16 + g4 * 4) = pv;
        }
    }
}

// ---------------- output[1] = nfeat passthrough
__global__ void copy_nfeat_k(const float4* __restrict__ s, float4* __restrict__ d, int n) {
    for (int i = blockIdx.x * blockDim.x + threadIdx.x; i < n; i += gridDim.x * blockDim.x)
        d[i] = s[i];
}

// ---------------- edge pass: h = silu(W1e·e + u[src] + v[dst] + b1);
// out = LN(h·W2 + b2) + e.
// 512 threads = 8 waves; 66 KB LDS; plain __launch_bounds__(512) — NEVER pass a
// 2nd arg (hipcc treats it as min-blocks/CU: (512,4)->64-reg budget->spill, seen
// R2/R5/R8). Occupancy is reg-pinned at 2 waves/SIMD (~192-256 total regs incl
// AGPR), so each wave processes 32 edges (two 16-edge MFMA groups L/R) for 2x
// in-flight memory + 2x MFMA per LDS A-frag read. Residual comes from live efk
// regs via 4-lane transpose (no efeat re-read); uv gathered at tile top, lands
// under GEMM1; efk refilled index-free during the store loop.
__global__ void __launch_bounds__(512)
edge_mlp_k(const float* __restrict__ efeat, const int* __restrict__ srci,
           const int* __restrict__ dsti, const u16* __restrict__ uv,
           const u16* __restrict__ pack, float* __restrict__ out) {
    extern __shared__ char smem[];
    const u16* w1e = (const u16*)smem;               // 32 KB
    const u16* w2  = (const u16*)(smem + 32768);     // 32 KB
    const float* cst = (const float*)(smem + 65536); // 2 KB
    const int tid = threadIdx.x;
    {
        const uint4* g = (const uint4*)pack;   // 4096 uint4 = 64 KB
        uint4* l = (uint4*)smem;
#pragma unroll
        for (int i = 0; i < 8; i++) l[tid + i * 512] = g[tid + i * 512];
        ((float*)(smem + 65536))[tid] = ((const float*)(pack + 65536))[tid];
    }
    __syncthreads();

    const int lane = tid & 63, wid = tid >> 6;
    const int col = lane & 15, g4 = (lane >> 4) & 3;
    const bool g4hi = (g4 & 2) != 0;
    const int sl_lo = col + ((g4 & 1) << 5);   // transpose source lanes
    const int sl_hi = sl_lo + 16;
    const float* cb1 = cst;
    const float* cb2 = cst + 128;
    const float* cg  = cst + 256;
    const float* cbb = cst + 384;

    int wt = blockIdx.x * 8 + wid;
    const int stride = (int)gridDim.x * 8;

    // prologue: tile-0 indices + efeat rows (B-layout) for both groups
    const int eL0 = wt * 32 + col, eR0 = eL0 + 16;
    int snL = srci[eL0], dnL = dsti[eL0];
    int snR = srci[eR0], dnR = dsti[eR0];
    float4 efkL[8], efkR[8];
    {
        const float* rowEL = efeat + (size_t)eL0 * 128;
        const float* rowER = efeat + (size_t)eR0 * 128;
#pragma unroll
        for (int q = 0; q < 4; q++) {
            const float4* pL = (const float4*)(rowEL + q * 32 + g4 * 8);
            efkL[2 * q] = pL[0]; efkL[2 * q + 1] = pL[1];
            const float4* pR = (const float4*)(rowER + q * 32 + g4 * 8);
            efkR[2 * q] = pR[0]; efkR[2 * q + 1] = pR[1];
        }
    }

    for (; wt < NT32; wt += stride) {
        // ---- uv gathers for this tile (both groups); land during GEMM1
        uint2 ugL[8], vgL[8], ugR[8], vgR[8];
        {
            const u16* upL = uv + (size_t)snL * 256;
            const u16* vpL = uv + (size_t)dnL * 256 + 128;
            const u16* upR = uv + (size_t)snR * 256;
            const u16* vpR = uv + (size_t)dnR * 256 + 128;
#pragma unroll
            for (int rt = 0; rt < 8; rt++) {
                ugL[rt] = *(const uint2*)(upL + rt * 16 + g4 * 4);
                vgL[rt] = *(const uint2*)(vpL + rt * 16 + g4 * 4);
                ugR[rt] = *(const uint2*)(upR + rt * 16 + g4 * 4);
                vgR[rt] = *(const uint2*)(vpR + rt * 16 + g4 * 4);
            }
        }

        // ---- next-tile indices + efeat row pointers
        const int wtn = wt + stride;
        const int base_n = ((wtn < NT32) ? wtn : wt) * 32;
        const int enL = base_n + col, enR = enL + 16;
        const int snL1 = srci[enL], dnL1 = dsti[enL];
        const int snR1 = srci[enR], dnR1 = dsti[enR];
        const float* rowELn = efeat + (size_t)enL * 128;
        const float* rowERn = efeat + (size_t)enR * 128;

        // ---- GEMM1 (K=128): shared A-frag, 2 MFMAs per LDS read
        f32x4 accL[8] = {}, accR[8] = {};
#pragma unroll
        for (int kt = 0; kt < 4; kt++) {
            bf16x8 bfL, bfR;
            {
                uint32_t* bu = (uint32_t*)&bfL;
                bu[0] = cvt2(efkL[2 * kt].x, efkL[2 * kt].y);
                bu[1] = cvt2(efkL[2 * kt].z, efkL[2 * kt].w);
                bu[2] = cvt2(efkL[2 * kt + 1].x, efkL[2 * kt + 1].y);
                bu[3] = cvt2(efkL[2 * kt + 1].z, efkL[2 * kt + 1].w);
            }
            {
                uint32_t* bu = (uint32_t*)&bfR;
                bu[0] = cvt2(efkR[2 * kt].x, efkR[2 * kt].y);
                bu[1] = cvt2(efkR[2 * kt].z, efkR[2 * kt].w);
                bu[2] = cvt2(efkR[2 * kt + 1].x, efkR[2 * kt + 1].y);
                bu[3] = cvt2(efkR[2 * kt + 1].z, efkR[2 * kt + 1].w);
            }
#pragma unroll
            for (int rt = 0; rt < 8; rt++) {
                bf16x8 a = *(const bf16x8*)(w1e + ((rt * 4 + kt) * 64 + lane) * 8);
                accL[rt] = __builtin_amdgcn_mfma_f32_16x16x32_bf16(a, bfL, accL[rt], 0, 0, 0);
                accR[rt] = __builtin_amdgcn_mfma_f32_16x16x32_bf16(a, bfR, accR[rt], 0, 0, 0);
            }
        }

        // ---- SiLU(acc + u + v + b1) -> packed bf16 (uvg consumed here)
        uint32_t hpkL[8][2], hpkR[8][2];
#pragma unroll
        for (int rt = 0; rt < 8; rt++) {
            float4 b1v = *(const float4*)(cb1 + rt * 16 + g4 * 4);
            {
                float x0 = accL[rt][0] + bflo(ugL[rt].x) + bflo(vgL[rt].x) + b1v.x;
                float x1 = accL[rt][1] + bfhi(ugL[rt].x) + bfhi(vgL[rt].x) + b1v.y;
                float x2 = accL[rt][2] + bflo(ugL[rt].y) + bflo(vgL[rt].y) + b1v.z;
                float x3 = accL[rt][3] + bfhi(ugL[rt].y) + bfhi(vgL[rt].y) + b1v.w;
                float s0 = x0 / (1.f + __expf(-x0)), s1 = x1 / (1.f + __expf(-x1));
                float s2 = x2 / (1.f + __expf(-x2)), s3 = x3 / (1.f + __expf(-x3));
                hpkL[rt][0] = cvt2(s0, s1); hpkL[rt][1] = cvt2(s2, s3);
            }
            {
                float x0 = accR[rt][0] + bflo(ugR[rt].x) + bflo(vgR[rt].x) + b1v.x;
                float x1 = accR[rt][1] + bfhi(ugR[rt].x) + bfhi(vgR[rt].x) + b1v.y;
                float x2 = accR[rt][2] + bflo(ugR[rt].y) + bflo(vgR[rt].y) + b1v.z;
                float x3 = accR[rt][3] + bfhi(ugR[rt].y) + bfhi(vgR[rt].y) + b1v.w;
                float s0 = x0 / (1.f + __expf(-x0)), s1 = x1 / (1.f + __expf(-x1));
                float s2 = x2 / (1.f + __expf(-x2)), s3 = x3 / (1.f + __expf(-x3));
                hpkR[rt][0] = cvt2(s0, s1); hpkR[rt][1] = cvt2(s2, s3);
            }
        }

        // ---- GEMM2 (acc reused; shared A-frag again)
#pragma unroll
        for (int ot = 0; ot < 8; ot++) {
            accL[ot] = (f32x4){0.f, 0.f, 0.f, 0.f};
            accR[ot] = (f32x4){0.f, 0.f, 0.f, 0.f};
        }
#pragma unroll
        for (int kt2 = 0; kt2 < 4; kt2++) {
            bf16x8 bfL, bfR;
            {
                uint32_t* bu = (uint32_t*)&bfL;
                bu[0] = hpkL[kt2][0];     bu[1] = hpkL[kt2][1];
                bu[2] = hpkL[kt2 + 4][0]; bu[3] = hpkL[kt2 + 4][1];
            }
            {
                uint32_t* bu = (uint32_t*)&bfR;
                bu[0] = hpkR[kt2][0];     bu[1] = hpkR[kt2][1];
                bu[2] = hpkR[kt2 + 4][0]; bu[3] = hpkR[kt2 + 4][1];
            }
#pragma unroll
            for (int ot = 0; ot < 8; ot++) {
                bf16x8 a = *(const bf16x8*)(w2 + ((ot * 4 + kt2) * 64 + lane) * 8);
                accL[ot] = __builtin_amdgcn_mfma_f32_16x16x32_bf16(a, bfL, accL[ot], 0, 0, 0);
                accR[ot] = __builtin_amdgcn_mfma_f32_16x16x32_bf16(a, bfR, accR[ot], 0, 0, 0);
            }
        }

        // ---- + b2, LN stats, normalize (both groups)
        float sL = 0.f, qL = 0.f, sR = 0.f, qR = 0.f;
#pragma unroll
        for (int ot = 0; ot < 8; ot++) {
            float4 b2v = *(const float4*)(cb2 + ot * 16 + g4 * 4);
#pragma unroll
            for (int r = 0; r < 4; r++) {
                float bb = ((const float*)&b2v)[r];
                float xL = accL[ot][r] + bb; accL[ot][r] = xL; sL += xL; qL += xL * xL;
                float xR = accR[ot][r] + bb; accR[ot][r] = xR; sR += xR; qR += xR * xR;
            }
        }
        sL += __shfl_xor(sL, 16); qL += __shfl_xor(qL, 16);
        sL += __shfl_xor(sL, 32); qL += __shfl_xor(qL, 32);
        sR += __shfl_xor(sR, 16); qR += __shfl_xor(qR, 16);
        sR += __shfl_xor(sR, 32); qR += __shfl_xor(qR, 32);
        const float meanL = sL * (1.f / 128.f);
        const float rstdL = rsqrtf(qL * (1.f / 128.f) - meanL * meanL + 1e-5f);
        const float meanR = sR * (1.f / 128.f);
        const float rstdR = rsqrtf(qR * (1.f / 128.f) - meanR * meanR + 1e-5f);
#pragma unroll
        for (int ot = 0; ot < 8; ot++) {
            float4 gv = *(const float4*)(cg + ot * 16 + g4 * 4);
            float4 bv = *(const float4*)(cbb + ot * 16 + g4 * 4);
#pragma unroll
            for (int r = 0; r < 4; r++) {
                float gg = ((const float*)&gv)[r], bb = ((const float*)&bv)[r];
                accL[ot][r] = (accL[ot][r] - meanL) * rstdL * gg + bb;
                accR[ot][r] = (accR[ot][r] - meanR) * rstdR * gg + bb;
            }
        }

        // ---- transpose D->B layout, + residual from live efk, store, refill
        float* opL = out + (size_t)(wt * 32 + col) * 128;
        float* opR = opL + 2048;   // +16 edges
#pragma unroll
        for (int qq = 0; qq < 4; qq++) {
            {   // group L
                float lo[4], hi[4];
#pragma unroll
                for (int r = 0; r < 4; r++) {
                    float av = accL[2 * qq][r], bv = accL[2 * qq + 1][r];
                    float la = __shfl(av, sl_lo), lb = __shfl(bv, sl_lo);
                    float ha = __shfl(av, sl_hi), hb = __shfl(bv, sl_hi);
                    lo[r] = g4hi ? lb : la;
                    hi[r] = g4hi ? hb : ha;
                }
                float4 olo, ohi;
                olo.x = lo[0] + efkL[2 * qq].x; olo.y = lo[1] + efkL[2 * qq].y;
                olo.z = lo[2] + efkL[2 * qq].z; olo.w = lo[3] + efkL[2 * qq].w;
                ohi.x = hi[0] + efkL[2 * qq + 1].x; ohi.y = hi[1] + efkL[2 * qq + 1].y;
                ohi.z = hi[2] + efkL[2 * qq + 1].z; ohi.w = hi[3] + efkL[2 * qq + 1].w;
                *(float4*)(opL + qq * 32 + g4 * 8) = olo;
                *(float4*)(opL + qq * 32 + g4 * 8 + 4) = ohi;
                const float4* p = (const float4*)(rowELn + qq * 32 + g4 * 8);
                efkL[2 * qq] = p[0]; efkL[2 * qq + 1] = p[1];
            }
            {   // group R
                float lo[4], hi[4];
#pragma unroll
                for (int r = 0; r < 4; r++) {
                    float av = accR[2 * qq][r], bv = accR[2 * qq + 1][r];
                    float la = __shfl(av, sl_lo), lb = __shfl(bv, sl_lo);
                    float ha = __shfl(av, sl_hi), hb = __shfl(bv, sl_hi);
                    lo[r] = g4hi ? lb : la;
                    hi[r] = g4hi ? hb : ha;
                }
                float4 olo, ohi;
                olo.x = lo[0] + efkR[2 * qq].x; olo.y = lo[1] + efkR[2 * qq].y;
                olo.z = lo[2] + efkR[2 * qq].z; olo.w = lo[3] + efkR[2 * qq].w;
                ohi.x = hi[0] + efkR[2 * qq + 1].x; ohi.y = hi[1] + efkR[2 * qq + 1].y;
                ohi.z = hi[2] + efkR[2 * qq + 1].z; ohi.w = hi[3] + efkR[2 * qq + 1].w;
                *(float4*)(opR + qq * 32 + g4 * 8) = olo;
                *(float4*)(opR + qq * 32 + g4 * 8 + 4) = ohi;
                const float4* p = (const float4*)(rowERn + qq * 32 + g4 * 8);
                efkR[2 * qq] = p[0]; efkR[2 * qq + 1] = p[1];
            }
        }

        snL = snL1; dnL = dnL1; snR = snR1; dnR = dnR1;
    }
}

extern "C" void kernel_launch(void* const* d_in, const int* in_sizes, int n_in,
                              void* d_out, int out_size, void* d_ws, size_t ws_size,
                              hipStream_t stream) {
    const float* efeat = (const float*)d_in[0];
    const float* nfeat = (const float*)d_in[1];
    const int* srci = (const int*)d_in[2];
    const int* dsti = (const int*)d_in[3];
    const float* W1 = (const float*)d_in[4];
    const float* b1 = (const float*)d_in[5];
    const float* W2 = (const float*)d_in[6];
    const float* b2 = (const float*)d_in[7];
    const float* lng = (const float*)d_in[8];
    const float* lnb = (const float*)d_in[9];
    float* out = (float*)d_out;

    const size_t pack_bytes = 133120;                 // 128 KB frags + 2 KB consts
    const size_t uv_bytes = (size_t)NN * 256 * 2;     // 51.2 MB bf16 uv
    u16 *pack, *uvb;
    if (ws_size >= pack_bytes + uv_bytes) {
        pack = (u16*)d_ws;
        uvb = (u16*)((char*)d_ws + pack_bytes);
    } else if (ws_size >= uv_bytes) {
        uvb = (u16*)d_ws;
        pack = (u16*)(out + (size_t)EE * 128);        // nfeat region; copy runs last
    } else {
        uvb = (u16*)(out + (size_t)EE * 128);         // exact fit; copy runs last
        pack = (ws_size >= pack_bytes) ? (u16*)d_ws
             : (u16*)(out + (size_t)EE * 128 - 33280); // edge-out tail (written last)
    }

    hipFuncSetAttribute(reinterpret_cast<const void*>(gen_uv_k),
                        hipFuncAttributeMaxDynamicSharedMemorySize, 65536);
    hipFuncSetAttribute(reinterpret_cast<const void*>(edge_mlp_k),
                        hipFuncAttributeMaxDynamicSharedMemorySize, 67584);

    pack_weights_k<<<258, 256, 0, stream>>>(W1, W2, b1, b2, lng, lnb, pack);
    gen_uv_k<<<512, 256, 65536, stream>>>(nfeat, pack, uvb);
    edge_mlp_k<<<256, 512, 67584, stream>>>(efeat, srci, dsti, uvb, pack, out);
    copy_nfeat_k<<<2048, 256, 0, stream>>>((const float4*)nfeat,
                                           (float4*)(out + (size_t)EE * 128),
                                           (NN * 128) / 4);
}